// Round 13
// baseline (159.843 us; speedup 1.0000x reference)
//
#include <hip/hip_runtime.h>

#define T_LEN 16384
#define K_CHUNK 64
#define BIGF 1e30f
typedef unsigned long long u64;

// softplus(x) = max(x,0) + log(1+exp(-|x|)) via hardware v_exp_f32/v_log_f32
__device__ __forceinline__ float sp0(float xv) {
    float e = __expf(-fabsf(xv));
    float l = __logf(1.0f + e);
    return fmaxf(xv, 0.0f) + l;
}

__global__ void mfl_zero(float* out) {
    if (threadIdx.x == 0) out[0] = 0.0f;
}

// Delta formulation: loss = sum_all softplus(x) + sum_runs delta(run),
// delta costs per element: {zero-choice: 0, one-choice: -x}.
// Short runs (<3): delta = -sum(x) (forced ones). Long runs: 3-state min-plus DP.
__global__ __launch_bounds__(256) void mfl_main(const float* __restrict__ x,
                                                const int* __restrict__ tgt,
                                                float* __restrict__ res,
                                                int total, float inv_total) {
    const int nchunks = total / K_CHUNK;
    const int stride = gridDim.x * blockDim.x;
    float acc0 = 0.0f, acc0b = 0.0f, acc1 = 0.0f;   // split chains for ILP

    for (int c = blockIdx.x * blockDim.x + threadIdx.x; c < nchunks; c += stride) {
        const int p0 = c * K_CHUNK;
        const int trow = p0 & (T_LEN - 1);          // 64 divides 16384: chunks stay in-row

        // ---- chunk loads: 16x float4 + 16x int4 (32 loads in flight), mask to u64
        float xs[64];
        u64 m = 0;
        const float4* xp = (const float4*)(x + p0);
        const int4*  tp = (const int4*)(tgt + p0);
        #pragma unroll
        for (int j = 0; j < 16; j++) {
            float4 v = xp[j];
            xs[4*j+0] = v.x; xs[4*j+1] = v.y; xs[4*j+2] = v.z; xs[4*j+3] = v.w;
        }
        #pragma unroll
        for (int j = 0; j < 16; j++) {
            int4 t = tp[j];
            m |= (u64)(t.x != 0) << (4*j+0);
            m |= (u64)(t.y != 0) << (4*j+1);
            m |= (u64)(t.z != 0) << (4*j+2);
            m |= (u64)(t.w != 0) << (4*j+3);
        }

        // ---- lookahead-8 into next chunk (overlapped with main loads; L2-deduped)
        const int pl = (p0 + K_CHUNK + 8 <= total) ? (p0 + K_CHUNK) : p0;
        float la[8];
        unsigned lm = 0;
        {
            const float4* lxp = (const float4*)(x + pl);
            const int4*  ltp = (const int4*)(tgt + pl);
            float4 a0 = lxp[0], a1 = lxp[1];
            int4   b0 = ltp[0], b1 = ltp[1];
            la[0]=a0.x; la[1]=a0.y; la[2]=a0.z; la[3]=a0.w;
            la[4]=a1.x; la[5]=a1.y; la[6]=a1.z; la[7]=a1.w;
            lm  = (unsigned)(b0.x!=0)      | ((unsigned)(b0.y!=0)<<1)
                | ((unsigned)(b0.z!=0)<<2) | ((unsigned)(b0.w!=0)<<3)
                | ((unsigned)(b1.x!=0)<<4) | ((unsigned)(b1.y!=0)<<5)
                | ((unsigned)(b1.z!=0)<<6) | ((unsigned)(b1.w!=0)<<7);
        }

        // ---- ownership: runs continuing from the previous chunk are owned there
        u64 amask = ~0ull;
        if (trow != 0 && tgt[p0 - 1] != 0) {
            u64 nm = ~m;
            amask = (nm == 0ull) ? 0ull : (~0ull << __builtin_ctzll(nm));
        }
        const u64 mm = m & amask;            // owned ones
        const u64 ss = mm & ~(mm << 1);      // run-start bits
        const u64 hm = (~mm) & (mm << 1);    // harvest bits (run ended at i-1)
        const u64 sh = hm & ((ss << 1) | (ss << 2));  // short-run (len<3) harvests

        // ---- branchless delta-DP, no length counter in the hot loop
        float v1 = BIGF, v2 = BIGF, v3 = 0.0f, s1 = 0.0f;
        #pragma unroll
        for (int i = 0; i < 64; i++) {
            const float xv = xs[i];
            const float sp = sp0(xv);
            if (i & 1) acc0b += sp; else acc0 += sp;      // two independent chains
            const bool harvf  = (hm >> i) & 1ull;
            const bool shortf = (sh >> i) & 1ull;
            const float m3 = fminf(v1, fminf(v2, v3));
            const float hv = shortf ? s1 : m3;
            acc1 += harvf ? hv : 0.0f;
            const bool startf = (ss >> i) & 1ull;         // segment-start reset
            const float r1 = startf ? BIGF : v1;
            const float r2 = startf ? BIGF : v2;
            const float r3 = startf ? 0.0f : v3;
            const float s1r = startf ? 0.0f : s1;
            v1 = r2 - xv;                                 // (0,1) <- (1,0) + (-x)
            v2 = r3;                                      // (1,0) <- (1,1) + 0
            v3 = fminf(r1, r3) - xv;                      // (1,1)
            s1 = s1r - xv;
        }

        // ---- cross-chunk tail: run length so far = count of leading ones in mm
        if ((mm >> 63) & 1ull) {
            const u64 nmm = ~mm;
            int leni = (nmm == 0ull) ? 64 : (int)__builtin_clzll(nmm);
            if (trow + K_CHUNK < T_LEN) {
                const unsigned g = lm & 0xFFu;
                const int k = (g == 0xFFu) ? 8 : (int)__builtin_ctz(~g & 0xFFu);
                #pragma unroll
                for (int j = 0; j < 8; j++) {
                    if (j < k) {
                        const float xv = la[j];
                        const float n1 = v2 - xv;
                        const float n2 = v3;
                        const float n3 = fminf(v1, v3) - xv;
                        v1 = n1; v2 = n2; v3 = n3;
                        s1 -= xv; leni++;
                    }
                }
                if (k == 8) {                    // run extends past lookahead (rare)
                    int t = trow + K_CHUNK + 8, pp = p0 + K_CHUNK + 8;
                    while (t < T_LEN) {          // 16B-aligned, stays in-row
                        const int4   tq = *(const int4*)(tgt + pp);
                        const float4 xq = *(const float4*)(x + pp);
                        const unsigned g4 = (unsigned)(tq.x != 0)
                                          | ((unsigned)(tq.y != 0) << 1)
                                          | ((unsigned)(tq.z != 0) << 2)
                                          | ((unsigned)(tq.w != 0) << 3);
                        const int k4 = (g4 == 0xFu) ? 4 : (int)__builtin_ctz(~g4 & 0xFu);
                        const float xv4[4] = {xq.x, xq.y, xq.z, xq.w};
                        #pragma unroll
                        for (int j = 0; j < 4; j++) {
                            if (j < k4) {
                                const float xv = xv4[j];
                                const float n1 = v2 - xv;
                                const float n2 = v3;
                                const float n3 = fminf(v1, v3) - xv;
                                v1 = n1; v2 = n2; v3 = n3;
                                s1 -= xv; leni++;
                            }
                        }
                        if (k4 < 4) break;
                        t += 4; pp += 4;
                    }
                }
            }
            acc1 += (leni < 3) ? s1 : fminf(v1, fminf(v2, v3));
        }
    }

    float acc = (acc0 + acc0b) + acc1;

    // ---- reduction: wave shuffle tree, LDS across 4 waves, one atomic/block
    #pragma unroll
    for (int off = 32; off > 0; off >>= 1)
        acc += __shfl_down(acc, off);

    __shared__ float smem[4];
    const int lane = threadIdx.x & 63;
    const int wid = threadIdx.x >> 6;
    if (lane == 0) smem[wid] = acc;
    __syncthreads();
    if (threadIdx.x == 0) {
        float b = (smem[0] + smem[1]) + (smem[2] + smem[3]);
        atomicAdd(res, b * inv_total);   // pre-scaled: fp32 atomic error ~1e-6
    }
}

extern "C" void kernel_launch(void* const* d_in, const int* in_sizes, int n_in,
                              void* d_out, int out_size, void* d_ws, size_t ws_size,
                              hipStream_t stream) {
    const float* x = (const float*)d_in[0];
    const int* tgt = (const int*)d_in[1];
    float* res = (float*)d_out;
    const int total = in_sizes[0];        // 1024 * 16384

    mfl_zero<<<1, 64, 0, stream>>>(res);

    const int threads = 256;
    const int nchunks = total / K_CHUNK;  // 262144 threads
    const int blocks = (nchunks + threads - 1) / threads;   // 1024
    mfl_main<<<blocks, threads, 0, stream>>>(x, tgt, res, total,
                                             1.0f / (float)total);
}